// Round 2
// baseline (4685.859 us; speedup 1.0000x reference)
//
#include <hip/hip_runtime.h>
#include <math.h>

#define DD 64

__device__ __forceinline__ float silu_f(float x) {
    return x / (1.0f + __expf(-x));
}

// ---------------- Kernel 1a: per-node linear transforms A,B (scalar), C,D (chiral) + out1 init
// Wave-private LDS slots; no barriers in the main loop.
__global__ __launch_bounds__(256) void node_transform_kernel(
    const float* __restrict__ ns, const float* __restrict__ nc,
    const float* __restrict__ Ws1, const float* __restrict__ Wc1,
    float* __restrict__ A, float* __restrict__ B,
    float* __restrict__ C, float* __restrict__ Dm,
    float* __restrict__ out1, int N)
{
    __shared__ float w1[128 * 64];
    __shared__ float wc1s[128 * 64];
    __shared__ float xs[4][2][64];
    __shared__ float ys[4][2][64];
    int tid = threadIdx.x;
    for (int i = tid; i < 128 * 64 / 4; i += 256) {
        ((float4*)w1)[i]   = ((const float4*)Ws1)[i];
        ((float4*)wc1s)[i] = ((const float4*)Wc1)[i];
    }
    __syncthreads();
    int wave = tid >> 6, lane = tid & 63;
    for (int nb = blockIdx.x * 8; nb < N; nb += gridDim.x * 8) {
        int n0 = nb + wave * 2;
        #pragma unroll
        for (int s = 0; s < 2; ++s) {
            int n = n0 + s;
            float xv = 0.f, yv = 0.f;
            if (n < N) { xv = ns[(size_t)n * DD + lane]; yv = nc[(size_t)n * DD + lane]; }
            xs[wave][s][lane] = xv;
            ys[wave][s][lane] = yv;
        }
        float aA[2] = {0.f, 0.f}, aB[2] = {0.f, 0.f}, aC[2] = {0.f, 0.f}, aD[2] = {0.f, 0.f};
        for (int k = 0; k < 64; ++k) {
            float wa  = w1[k * 64 + lane];
            float wb  = w1[(64 + k) * 64 + lane];
            float wca = wc1s[k * 64 + lane];
            float wcb = wc1s[(64 + k) * 64 + lane];
            #pragma unroll
            for (int s = 0; s < 2; ++s) {
                float xk = xs[wave][s][k];
                float yk = ys[wave][s][k];
                aA[s] += xk * wa;  aB[s] += xk * wb;
                aC[s] += yk * wca; aD[s] += yk * wcb;
            }
        }
        #pragma unroll
        for (int s = 0; s < 2; ++s) {
            int n = n0 + s;
            if (n < N) {
                A[(size_t)n * DD + lane]  = aA[s];
                B[(size_t)n * DD + lane]  = aB[s];
                C[(size_t)n * DD + lane]  = aC[s];
                Dm[(size_t)n * DD + lane] = aD[s];
                out1[(size_t)n * DD + lane] = ys[wave][s][lane];
            }
        }
    }
}

// ---------------- Kernel 1b: Vv = nv@WV + bV, norm over the 3-axis, out0 init, out2 init
__global__ __launch_bounds__(256) void node_vector_kernel(
    const float* __restrict__ ns, const float* __restrict__ nv,
    const float* __restrict__ WV, const float* __restrict__ bV,
    float* __restrict__ out0, float* __restrict__ out2, int N)
{
    __shared__ float wv[64 * 64];
    __shared__ float vs[4][2][3][64];
    int tid = threadIdx.x;
    for (int i = tid; i < 64 * 64 / 4; i += 256)
        ((float4*)wv)[i] = ((const float4*)WV)[i];
    __syncthreads();
    int wave = tid >> 6, lane = tid & 63;
    float bVj = bV[lane];
    for (int nb = blockIdx.x * 8; nb < N; nb += gridDim.x * 8) {
        int n0 = nb + wave * 2;
        #pragma unroll
        for (int s = 0; s < 2; ++s) {
            int n = n0 + s;
            float v0 = 0.f, v1 = 0.f, v2 = 0.f;
            if (n < N) {
                v0 = nv[((size_t)n * 3 + 0) * DD + lane];
                v1 = nv[((size_t)n * 3 + 1) * DD + lane];
                v2 = nv[((size_t)n * 3 + 2) * DD + lane];
            }
            vs[wave][s][0][lane] = v0; vs[wave][s][1][lane] = v1; vs[wave][s][2][lane] = v2;
        }
        float a0[2], a1[2], a2[2];
        #pragma unroll
        for (int s = 0; s < 2; ++s) { a0[s] = bVj; a1[s] = bVj; a2[s] = bVj; }
        for (int k = 0; k < 64; ++k) {
            float w = wv[k * 64 + lane];
            #pragma unroll
            for (int s = 0; s < 2; ++s) {
                a0[s] += vs[wave][s][0][k] * w;
                a1[s] += vs[wave][s][1][k] * w;
                a2[s] += vs[wave][s][2][k] * w;
            }
        }
        #pragma unroll
        for (int s = 0; s < 2; ++s) {
            int n = n0 + s;
            if (n < N) {
                float norm = sqrtf(a0[s] * a0[s] + a1[s] * a1[s] + a2[s] * a2[s]);
                float x = ns[(size_t)n * DD + lane];
                out0[(size_t)n * DD + lane] = x * (1.f + norm);
                out2[((size_t)n * 3 + 0) * DD + lane] = vs[wave][s][0][lane];
                out2[((size_t)n * 3 + 1) * DD + lane] = vs[wave][s][1][lane];
                out2[((size_t)n * 3 + 2) * DD + lane] = vs[wave][s][2][lane];
            }
        }
    }
}

// ---------------- Kernel 2: edges — 512 threads, wave-independent, 1-deep pipelined
#define WPB 8
#define EPW 4
__global__ __launch_bounds__(512) void edge_kernel(
    const float* __restrict__ A, const float* __restrict__ B,
    const float* __restrict__ nv, const float* __restrict__ pos,
    const int* __restrict__ eidx,
    const float* __restrict__ bs1, const float* __restrict__ Ws2, const float* __restrict__ bs2,
    float* __restrict__ out0, float* __restrict__ out2, int E)
{
    __shared__ float w2[64 * 192];
    __shared__ float hsh[WPB][EPW][64];
    int tid = threadIdx.x;
    for (int i = tid; i < 64 * 192 / 4; i += 512)
        ((float4*)w2)[i] = ((const float4*)Ws2)[i];
    __syncthreads();
    int wave = tid >> 6, lane = tid & 63;
    float b1  = bs1[lane];
    float b2v = bs2[lane], b2e = bs2[64 + lane], b2s = bs2[128 + lane];

    long nG = ((long)E + EPW - 1) / EPW;
    long wid = (long)blockIdx.x * WPB + wave;
    long wstride = (long)gridDim.x * WPB;

    int   ni0[EPW], ni1[EPW];
    float nA[EPW], nB[EPW], nV0[EPW], nV1[EPW], nV2[EPW];

    long g = wid;
    if (g < nG) {
        #pragma unroll
        for (int e = 0; e < EPW; ++e) {
            long eid = g * EPW + e;
            int i0 = 0, i1 = 0;
            if (eid < E) { i0 = eidx[2 * eid]; i1 = eidx[2 * eid + 1]; }
            ni0[e] = i0; ni1[e] = i1;
        }
        #pragma unroll
        for (int e = 0; e < EPW; ++e) {
            nA[e]  = A[(size_t)ni0[e] * DD + lane];
            nB[e]  = B[(size_t)ni1[e] * DD + lane];
            nV0[e] = nv[((size_t)ni1[e] * 3 + 0) * DD + lane];
            nV1[e] = nv[((size_t)ni1[e] * 3 + 1) * DD + lane];
            nV2[e] = nv[((size_t)ni1[e] * 3 + 2) * DD + lane];
        }
    }
    for (; g < nG; g += wstride) {
        // phase 1: consume staged A/B -> h, stash cur aux regs
        int   ci0[EPW], ci1[EPW];
        float cV0[EPW], cV1[EPW], cV2[EPW];
        #pragma unroll
        for (int e = 0; e < EPW; ++e) {
            ci0[e] = ni0[e]; ci1[e] = ni1[e];
            cV0[e] = nV0[e]; cV1[e] = nV1[e]; cV2[e] = nV2[e];
            float h = silu_f(nA[e] + nB[e] + b1);
            hsh[wave][e][lane] = h;
        }
        // phase 2: issue next-group gathers (latency hides under matvec below)
        long gn = g + wstride;
        if (gn < nG) {
            #pragma unroll
            for (int e = 0; e < EPW; ++e) {
                long eid = gn * EPW + e;
                int i0 = 0, i1 = 0;
                if (eid < E) { i0 = eidx[2 * eid]; i1 = eidx[2 * eid + 1]; }
                ni0[e] = i0; ni1[e] = i1;
            }
            #pragma unroll
            for (int e = 0; e < EPW; ++e) {
                nA[e]  = A[(size_t)ni0[e] * DD + lane];
                nB[e]  = B[(size_t)ni1[e] * DD + lane];
                nV0[e] = nv[((size_t)ni1[e] * 3 + 0) * DD + lane];
                nV1[e] = nv[((size_t)ni1[e] * 3 + 1) * DD + lane];
                nV2[e] = nv[((size_t)ni1[e] * 3 + 2) * DD + lane];
            }
        }
        // phase 3: matvec h @ Ws2 (wave-private LDS; compiler inserts lgkmcnt waits)
        float agv[EPW], age[EPW], ass[EPW];
        #pragma unroll
        for (int e = 0; e < EPW; ++e) { agv[e] = 0.f; age[e] = 0.f; ass[e] = 0.f; }
        for (int k4 = 0; k4 < 64; k4 += 4) {
            float4 hk[EPW];
            #pragma unroll
            for (int e = 0; e < EPW; ++e) hk[e] = *(const float4*)&hsh[wave][e][k4];
            #pragma unroll
            for (int kk = 0; kk < 4; ++kk) {
                int k = k4 + kk;
                float w0  = w2[k * 192 + lane];
                float w1v = w2[k * 192 + 64 + lane];
                float w2v = w2[k * 192 + 128 + lane];
                #pragma unroll
                for (int e = 0; e < EPW; ++e) {
                    float hv = (&hk[e].x)[kk];
                    agv[e] += hv * w0; age[e] += hv * w1v; ass[e] += hv * w2v;
                }
            }
        }
        // phase 4: scatter
        #pragma unroll
        for (int e = 0; e < EPW; ++e) {
            long eid = g * EPW + e;
            if (eid >= E) break;
            int i0 = ci0[e], i1 = ci1[e];
            unsafeAtomicAdd(&out0[(size_t)i0 * DD + lane], ass[e] + b2s);
            float rx = pos[(size_t)i1 * 3 + 0] - pos[(size_t)i0 * 3 + 0];
            float ry = pos[(size_t)i1 * 3 + 1] - pos[(size_t)i0 * 3 + 1];
            float rz = pos[(size_t)i1 * 3 + 2] - pos[(size_t)i0 * 3 + 2];
            float gv = agv[e] + b2v, ge = age[e] + b2e;
            unsafeAtomicAdd(&out2[((size_t)i0 * 3 + 0) * DD + lane], gv * cV0[e] + ge * rx);
            unsafeAtomicAdd(&out2[((size_t)i0 * 3 + 1) * DD + lane], gv * cV1[e] + ge * ry);
            unsafeAtomicAdd(&out2[((size_t)i0 * 3 + 2) * DD + lane], gv * cV2[e] + ge * rz);
        }
    }
}

// ---------------- Kernel 3: triplets — 512 threads, wave-independent, 1-deep pipelined
#define TWPB 8
#define TPW 4
__global__ __launch_bounds__(512) void triplet_kernel(
    const float* __restrict__ C, const float* __restrict__ Dm,
    const float* __restrict__ pos, const int* __restrict__ tidx,
    const float* __restrict__ bc1, const float* __restrict__ Wc2, const float* __restrict__ bc2,
    float* __restrict__ out1, int T)
{
    __shared__ float w[64 * 64];
    __shared__ float hsh[TWPB][TPW][64];
    int tid = threadIdx.x;
    for (int i = tid; i < 64 * 64 / 4; i += 512)
        ((float4*)w)[i] = ((const float4*)Wc2)[i];
    __syncthreads();
    int wave = tid >> 6, lane = tid & 63;
    float b1 = bc1[lane];
    float b2 = bc2[lane] * 3.0f;

    long nG = ((long)T + TPW - 1) / TPW;
    long wid = (long)blockIdx.x * TWPB + wave;
    long wstride = (long)gridDim.x * TWPB;

    int   nb_[TPW], nt1[TPW], nt2[TPW], nt3[TPW];
    float nC[TPW], nD1[TPW], nD2[TPW], nD3[TPW];

    long g = wid;
    if (g < nG) {
        #pragma unroll
        for (int e = 0; e < TPW; ++e) {
            long t = g * TPW + e;
            int b = 0, t1 = 0, t2 = 0, t3 = 0;
            if (t < T) { b = tidx[4*t]; t1 = tidx[4*t+1]; t2 = tidx[4*t+2]; t3 = tidx[4*t+3]; }
            nb_[e] = b; nt1[e] = t1; nt2[e] = t2; nt3[e] = t3;
        }
        #pragma unroll
        for (int e = 0; e < TPW; ++e) {
            nC[e]  = C[(size_t)nb_[e] * DD + lane];
            nD1[e] = Dm[(size_t)nt1[e] * DD + lane];
            nD2[e] = Dm[(size_t)nt2[e] * DD + lane];
            nD3[e] = Dm[(size_t)nt3[e] * DD + lane];
        }
    }
    for (; g < nG; g += wstride) {
        // phase 1: h from staged rows
        int cb[TPW], c1[TPW], c2[TPW], c3[TPW];
        #pragma unroll
        for (int e = 0; e < TPW; ++e) {
            cb[e] = nb_[e]; c1[e] = nt1[e]; c2[e] = nt2[e]; c3[e] = nt3[e];
            float hb = nC[e] + b1;
            float h = silu_f(hb + nD1[e]) + silu_f(hb + nD2[e]) + silu_f(hb + nD3[e]);
            hsh[wave][e][lane] = h;
        }
        // phase 2: issue next-group gathers
        long gn = g + wstride;
        if (gn < nG) {
            #pragma unroll
            for (int e = 0; e < TPW; ++e) {
                long t = gn * TPW + e;
                int b = 0, t1 = 0, t2 = 0, t3 = 0;
                if (t < T) { b = tidx[4*t]; t1 = tidx[4*t+1]; t2 = tidx[4*t+2]; t3 = tidx[4*t+3]; }
                nb_[e] = b; nt1[e] = t1; nt2[e] = t2; nt3[e] = t3;
            }
            #pragma unroll
            for (int e = 0; e < TPW; ++e) {
                nC[e]  = C[(size_t)nb_[e] * DD + lane];
                nD1[e] = Dm[(size_t)nt1[e] * DD + lane];
                nD2[e] = Dm[(size_t)nt2[e] * DD + lane];
                nD3[e] = Dm[(size_t)nt3[e] * DD + lane];
            }
        }
        // phase 3: stp in f64 (matches np f64 near the 1/(stp+0.01) pole)
        float inv[TPW];
        #pragma unroll
        for (int e = 0; e < TPW; ++e) {
            int b = cb[e], t1 = c1[e], t2 = c2[e], t3 = c3[e];
            double pbx = pos[(size_t)b*3], pby = pos[(size_t)b*3+1], pbz = pos[(size_t)b*3+2];
            double r1x = pbx - pos[(size_t)t1*3], r1y = pby - pos[(size_t)t1*3+1], r1z = pbz - pos[(size_t)t1*3+2];
            double r2x = pbx - pos[(size_t)t2*3], r2y = pby - pos[(size_t)t2*3+1], r2z = pbz - pos[(size_t)t2*3+2];
            double r3x = pbx - pos[(size_t)t3*3], r3y = pby - pos[(size_t)t3*3+1], r3z = pbz - pos[(size_t)t3*3+2];
            double cx = r2y * r3z - r2z * r3y;
            double cy = r2z * r3x - r2x * r3z;
            double cz = r2x * r3y - r2y * r3x;
            double stp = r1x * cx + r1y * cy + r1z * cz;
            inv[e] = (float)(1.0 / (stp + 0.01));
        }
        // phase 4: matvec
        float acc[TPW];
        #pragma unroll
        for (int e = 0; e < TPW; ++e) acc[e] = 0.f;
        for (int k4 = 0; k4 < 64; k4 += 4) {
            float4 hk[TPW];
            #pragma unroll
            for (int e = 0; e < TPW; ++e) hk[e] = *(const float4*)&hsh[wave][e][k4];
            #pragma unroll
            for (int kk = 0; kk < 4; ++kk) {
                float wk = w[(k4 + kk) * 64 + lane];
                #pragma unroll
                for (int e = 0; e < TPW; ++e) acc[e] += (&hk[e].x)[kk] * wk;
            }
        }
        // phase 5: scatter
        #pragma unroll
        for (int e = 0; e < TPW; ++e) {
            long t = g * TPW + e;
            if (t >= T) break;
            unsafeAtomicAdd(&out1[(size_t)cb[e] * DD + lane], (acc[e] + b2) * inv[e]);
        }
    }
}

extern "C" void kernel_launch(void* const* d_in, const int* in_sizes, int n_in,
                              void* d_out, int out_size, void* d_ws, size_t ws_size,
                              hipStream_t stream)
{
    const float* ns  = (const float*)d_in[0];
    const float* nc  = (const float*)d_in[1];
    const float* nv  = (const float*)d_in[2];
    const float* pos = (const float*)d_in[3];
    const int* eidx  = (const int*)d_in[4];
    const int* tidx  = (const int*)d_in[5];
    const float* Ws1 = (const float*)d_in[6];
    const float* bs1 = (const float*)d_in[7];
    const float* Ws2 = (const float*)d_in[8];
    const float* bs2 = (const float*)d_in[9];
    const float* Wc1 = (const float*)d_in[10];
    const float* bc1 = (const float*)d_in[11];
    const float* Wc2 = (const float*)d_in[12];
    const float* bc2 = (const float*)d_in[13];
    const float* WV  = (const float*)d_in[14];
    const float* bV  = (const float*)d_in[15];

    int N = in_sizes[0] / 64;
    int E = in_sizes[4] / 2;
    int T = in_sizes[5] / 4;

    float* out0 = (float*)d_out;
    float* out1 = out0 + (size_t)N * 64;
    float* out2 = out1 + (size_t)N * 64;

    float* A  = (float*)d_ws;
    float* B  = A + (size_t)N * 64;
    float* C  = B + (size_t)N * 64;
    float* Dm = C + (size_t)N * 64;

    node_transform_kernel<<<1024, 256, 0, stream>>>(ns, nc, Ws1, Wc1, A, B, C, Dm, out1, N);
    node_vector_kernel<<<1024, 256, 0, stream>>>(ns, nv, WV, bV, out0, out2, N);
    edge_kernel<<<1024, 512, 0, stream>>>(A, B, nv, pos, eidx, bs1, Ws2, bs2, out0, out2, E);
    triplet_kernel<<<1024, 512, 0, stream>>>(C, Dm, pos, tidx, bc1, Wc2, bc2, out1, T);
}

// Round 3
// 1415.942 us; speedup vs baseline: 3.3094x; 3.3094x over previous
//
#include <hip/hip_runtime.h>
#include <math.h>

#define DD 64

__device__ __forceinline__ float silu_f(float x) {
    return x / (1.0f + __expf(-x));
}

// ---------------- Kernel 1a: per-node linear transforms A,B (scalar), C,D (chiral) + out1 init
// Wave-private LDS slots; no barriers in the main loop.
__global__ __launch_bounds__(256) void node_transform_kernel(
    const float* __restrict__ ns, const float* __restrict__ nc,
    const float* __restrict__ Ws1, const float* __restrict__ Wc1,
    float* __restrict__ A, float* __restrict__ B,
    float* __restrict__ C, float* __restrict__ Dm,
    float* __restrict__ out1, int N)
{
    __shared__ float w1[128 * 64];
    __shared__ float wc1s[128 * 64];
    __shared__ float xs[4][2][64];
    __shared__ float ys[4][2][64];
    int tid = threadIdx.x;
    for (int i = tid; i < 128 * 64 / 4; i += 256) {
        ((float4*)w1)[i]   = ((const float4*)Ws1)[i];
        ((float4*)wc1s)[i] = ((const float4*)Wc1)[i];
    }
    __syncthreads();
    int wave = tid >> 6, lane = tid & 63;
    for (int nb = blockIdx.x * 8; nb < N; nb += gridDim.x * 8) {
        int n0 = nb + wave * 2;
        #pragma unroll
        for (int s = 0; s < 2; ++s) {
            int n = n0 + s;
            float xv = 0.f, yv = 0.f;
            if (n < N) { xv = ns[(size_t)n * DD + lane]; yv = nc[(size_t)n * DD + lane]; }
            xs[wave][s][lane] = xv;
            ys[wave][s][lane] = yv;
        }
        float aA[2] = {0.f, 0.f}, aB[2] = {0.f, 0.f}, aC[2] = {0.f, 0.f}, aD[2] = {0.f, 0.f};
        for (int k = 0; k < 64; ++k) {
            float wa  = w1[k * 64 + lane];
            float wb  = w1[(64 + k) * 64 + lane];
            float wca = wc1s[k * 64 + lane];
            float wcb = wc1s[(64 + k) * 64 + lane];
            #pragma unroll
            for (int s = 0; s < 2; ++s) {
                float xk = xs[wave][s][k];
                float yk = ys[wave][s][k];
                aA[s] += xk * wa;  aB[s] += xk * wb;
                aC[s] += yk * wca; aD[s] += yk * wcb;
            }
        }
        #pragma unroll
        for (int s = 0; s < 2; ++s) {
            int n = n0 + s;
            if (n < N) {
                A[(size_t)n * DD + lane]  = aA[s];
                B[(size_t)n * DD + lane]  = aB[s];
                C[(size_t)n * DD + lane]  = aC[s];
                Dm[(size_t)n * DD + lane] = aD[s];
                out1[(size_t)n * DD + lane] = ys[wave][s][lane];
            }
        }
    }
}

// ---------------- Kernel 1b: Vv = nv@WV + bV, norm over the 3-axis, out0 init, out2 init
__global__ __launch_bounds__(256) void node_vector_kernel(
    const float* __restrict__ ns, const float* __restrict__ nv,
    const float* __restrict__ WV, const float* __restrict__ bV,
    float* __restrict__ out0, float* __restrict__ out2, int N)
{
    __shared__ float wv[64 * 64];
    __shared__ float vs[4][2][3][64];
    int tid = threadIdx.x;
    for (int i = tid; i < 64 * 64 / 4; i += 256)
        ((float4*)wv)[i] = ((const float4*)WV)[i];
    __syncthreads();
    int wave = tid >> 6, lane = tid & 63;
    float bVj = bV[lane];
    for (int nb = blockIdx.x * 8; nb < N; nb += gridDim.x * 8) {
        int n0 = nb + wave * 2;
        #pragma unroll
        for (int s = 0; s < 2; ++s) {
            int n = n0 + s;
            float v0 = 0.f, v1 = 0.f, v2 = 0.f;
            if (n < N) {
                v0 = nv[((size_t)n * 3 + 0) * DD + lane];
                v1 = nv[((size_t)n * 3 + 1) * DD + lane];
                v2 = nv[((size_t)n * 3 + 2) * DD + lane];
            }
            vs[wave][s][0][lane] = v0; vs[wave][s][1][lane] = v1; vs[wave][s][2][lane] = v2;
        }
        float a0[2], a1[2], a2[2];
        #pragma unroll
        for (int s = 0; s < 2; ++s) { a0[s] = bVj; a1[s] = bVj; a2[s] = bVj; }
        for (int k = 0; k < 64; ++k) {
            float w = wv[k * 64 + lane];
            #pragma unroll
            for (int s = 0; s < 2; ++s) {
                a0[s] += vs[wave][s][0][k] * w;
                a1[s] += vs[wave][s][1][k] * w;
                a2[s] += vs[wave][s][2][k] * w;
            }
        }
        #pragma unroll
        for (int s = 0; s < 2; ++s) {
            int n = n0 + s;
            if (n < N) {
                float norm = sqrtf(a0[s] * a0[s] + a1[s] * a1[s] + a2[s] * a2[s]);
                float x = ns[(size_t)n * DD + lane];
                out0[(size_t)n * DD + lane] = x * (1.f + norm);
                out2[((size_t)n * 3 + 0) * DD + lane] = vs[wave][s][0][lane];
                out2[((size_t)n * 3 + 1) * DD + lane] = vs[wave][s][1][lane];
                out2[((size_t)n * 3 + 2) * DD + lane] = vs[wave][s][2][lane];
            }
        }
    }
}

// ---------------- Kernel 2: edges — round-1 structure, barriers removed (hsh is wave-private)
#define EPW 8
__global__ __launch_bounds__(256) void edge_kernel(
    const float* __restrict__ A, const float* __restrict__ B,
    const float* __restrict__ nv, const float* __restrict__ pos,
    const int* __restrict__ eidx,
    const float* __restrict__ bs1, const float* __restrict__ Ws2, const float* __restrict__ bs2,
    float* __restrict__ out0, float* __restrict__ out2, int E)
{
    __shared__ float w2[64 * 192];
    __shared__ float hsh[4][EPW][64];
    int tid = threadIdx.x;
    for (int i = tid; i < 64 * 192 / 4; i += 256)
        ((float4*)w2)[i] = ((const float4*)Ws2)[i];
    __syncthreads();
    int wave = tid >> 6, lane = tid & 63;
    float b1  = bs1[lane];
    float b2v = bs2[lane], b2e = bs2[64 + lane], b2s = bs2[128 + lane];
    for (long bb = (long)blockIdx.x * (4 * EPW); bb < E; bb += (long)gridDim.x * (4 * EPW)) {
        long e0b = bb + wave * EPW;
        int i0a[EPW], i1a[EPW];
        // gather + h  (wave-private; compiler-inserted lgkmcnt orders LDS write->read)
        #pragma unroll
        for (int e = 0; e < EPW; ++e) {
            long eid = e0b + e;
            int i0 = 0, i1 = 0;
            if (eid < E) { int2 p = ((const int2*)eidx)[eid]; i0 = p.x; i1 = p.y; }
            i0a[e] = i0; i1a[e] = i1;
        }
        #pragma unroll
        for (int e = 0; e < EPW; ++e) {
            long eid = e0b + e;
            float h = 0.f;
            if (eid < E)
                h = silu_f(A[(size_t)i0a[e] * DD + lane] + B[(size_t)i1a[e] * DD + lane] + b1);
            hsh[wave][e][lane] = h;
        }
        // matvec h @ Ws2
        float agv[EPW], age[EPW], ass[EPW];
        #pragma unroll
        for (int e = 0; e < EPW; ++e) { agv[e] = 0.f; age[e] = 0.f; ass[e] = 0.f; }
        for (int k4 = 0; k4 < 64; k4 += 4) {
            float4 hk[EPW];
            #pragma unroll
            for (int e = 0; e < EPW; ++e) hk[e] = *(const float4*)&hsh[wave][e][k4];
            #pragma unroll
            for (int kk = 0; kk < 4; ++kk) {
                int k = k4 + kk;
                float w0  = w2[k * 192 + lane];
                float w1v = w2[k * 192 + 64 + lane];
                float w2v = w2[k * 192 + 128 + lane];
                #pragma unroll
                for (int e = 0; e < EPW; ++e) {
                    float hv = (&hk[e].x)[kk];
                    agv[e] += hv * w0; age[e] += hv * w1v; ass[e] += hv * w2v;
                }
            }
        }
        // scatter (nv/pos loaded at use; 8-edge unroll gives MLP)
        #pragma unroll
        for (int e = 0; e < EPW; ++e) {
            long eid = e0b + e;
            if (eid >= E) break;
            int i0 = i0a[e], i1 = i1a[e];
            unsafeAtomicAdd(&out0[(size_t)i0 * DD + lane], ass[e] + b2s);
            float rx = pos[(size_t)i1 * 3 + 0] - pos[(size_t)i0 * 3 + 0];
            float ry = pos[(size_t)i1 * 3 + 1] - pos[(size_t)i0 * 3 + 1];
            float rz = pos[(size_t)i1 * 3 + 2] - pos[(size_t)i0 * 3 + 2];
            float v0 = nv[((size_t)i1 * 3 + 0) * DD + lane];
            float v1 = nv[((size_t)i1 * 3 + 1) * DD + lane];
            float v2 = nv[((size_t)i1 * 3 + 2) * DD + lane];
            float gv = agv[e] + b2v, ge = age[e] + b2e;
            unsafeAtomicAdd(&out2[((size_t)i0 * 3 + 0) * DD + lane], gv * v0 + ge * rx);
            unsafeAtomicAdd(&out2[((size_t)i0 * 3 + 1) * DD + lane], gv * v1 + ge * ry);
            unsafeAtomicAdd(&out2[((size_t)i0 * 3 + 2) * DD + lane], gv * v2 + ge * rz);
        }
    }
}

// ---------------- Kernel 3: triplets — round-1 structure, barriers removed
#define TPW 8
__global__ __launch_bounds__(256) void triplet_kernel(
    const float* __restrict__ C, const float* __restrict__ Dm,
    const float* __restrict__ pos, const int* __restrict__ tidx,
    const float* __restrict__ bc1, const float* __restrict__ Wc2, const float* __restrict__ bc2,
    float* __restrict__ out1, int T)
{
    __shared__ float w[64 * 64];
    __shared__ float hsh[4][TPW][64];
    int tid = threadIdx.x;
    for (int i = tid; i < 64 * 64 / 4; i += 256)
        ((float4*)w)[i] = ((const float4*)Wc2)[i];
    __syncthreads();
    int wave = tid >> 6, lane = tid & 63;
    float b1 = bc1[lane];
    float b2 = bc2[lane] * 3.0f;
    for (long bb = (long)blockIdx.x * (4 * TPW); bb < T; bb += (long)gridDim.x * (4 * TPW)) {
        long t0 = bb + wave * TPW;
        int ib[TPW]; float inv[TPW];
        #pragma unroll
        for (int e = 0; e < TPW; ++e) {
            long t = t0 + e;
            float h = 0.f;
            int b = 0;
            float invv = 0.f;
            if (t < T) {
                int4 q = ((const int4*)tidx)[t];
                b = q.x; int t1 = q.y, t2 = q.z, t3 = q.w;
                float hb = C[(size_t)b * DD + lane] + b1;
                float h1 = silu_f(hb + Dm[(size_t)t1 * DD + lane]);
                float h2 = silu_f(hb + Dm[(size_t)t2 * DD + lane]);
                float h3 = silu_f(hb + Dm[(size_t)t3 * DD + lane]);
                h = h1 + h2 + h3;
                double pbx = pos[(size_t)b * 3], pby = pos[(size_t)b * 3 + 1], pbz = pos[(size_t)b * 3 + 2];
                double r1x = pbx - pos[(size_t)t1 * 3], r1y = pby - pos[(size_t)t1 * 3 + 1], r1z = pbz - pos[(size_t)t1 * 3 + 2];
                double r2x = pbx - pos[(size_t)t2 * 3], r2y = pby - pos[(size_t)t2 * 3 + 1], r2z = pbz - pos[(size_t)t2 * 3 + 2];
                double r3x = pbx - pos[(size_t)t3 * 3], r3y = pby - pos[(size_t)t3 * 3 + 1], r3z = pbz - pos[(size_t)t3 * 3 + 2];
                double cx = r2y * r3z - r2z * r3y;
                double cy = r2z * r3x - r2x * r3z;
                double cz = r2x * r3y - r2y * r3x;
                double stp = r1x * cx + r1y * cy + r1z * cz;
                invv = (float)(1.0 / (stp + 0.01));
            }
            ib[e] = b; inv[e] = invv;
            hsh[wave][e][lane] = h;
        }
        float acc[TPW];
        #pragma unroll
        for (int e = 0; e < TPW; ++e) acc[e] = 0.f;
        for (int k4 = 0; k4 < 64; k4 += 4) {
            float4 hk[TPW];
            #pragma unroll
            for (int e = 0; e < TPW; ++e) hk[e] = *(const float4*)&hsh[wave][e][k4];
            #pragma unroll
            for (int kk = 0; kk < 4; ++kk) {
                float wk = w[(k4 + kk) * 64 + lane];
                #pragma unroll
                for (int e = 0; e < TPW; ++e) acc[e] += (&hk[e].x)[kk] * wk;
            }
        }
        #pragma unroll
        for (int e = 0; e < TPW; ++e) {
            long t = t0 + e;
            if (t >= T) break;
            unsafeAtomicAdd(&out1[(size_t)ib[e] * DD + lane], (acc[e] + b2) * inv[e]);
        }
    }
}

extern "C" void kernel_launch(void* const* d_in, const int* in_sizes, int n_in,
                              void* d_out, int out_size, void* d_ws, size_t ws_size,
                              hipStream_t stream)
{
    const float* ns  = (const float*)d_in[0];
    const float* nc  = (const float*)d_in[1];
    const float* nv  = (const float*)d_in[2];
    const float* pos = (const float*)d_in[3];
    const int* eidx  = (const int*)d_in[4];
    const int* tidx  = (const int*)d_in[5];
    const float* Ws1 = (const float*)d_in[6];
    const float* bs1 = (const float*)d_in[7];
    const float* Ws2 = (const float*)d_in[8];
    const float* bs2 = (const float*)d_in[9];
    const float* Wc1 = (const float*)d_in[10];
    const float* bc1 = (const float*)d_in[11];
    const float* Wc2 = (const float*)d_in[12];
    const float* bc2 = (const float*)d_in[13];
    const float* WV  = (const float*)d_in[14];
    const float* bV  = (const float*)d_in[15];

    int N = in_sizes[0] / 64;
    int E = in_sizes[4] / 2;
    int T = in_sizes[5] / 4;

    float* out0 = (float*)d_out;
    float* out1 = out0 + (size_t)N * 64;
    float* out2 = out1 + (size_t)N * 64;

    float* A  = (float*)d_ws;
    float* B  = A + (size_t)N * 64;
    float* C  = B + (size_t)N * 64;
    float* Dm = C + (size_t)N * 64;

    node_transform_kernel<<<2048, 256, 0, stream>>>(ns, nc, Ws1, Wc1, A, B, C, Dm, out1, N);
    node_vector_kernel<<<2048, 256, 0, stream>>>(ns, nv, WV, bV, out0, out2, N);
    edge_kernel<<<2048, 256, 0, stream>>>(A, B, nv, pos, eidx, bs1, Ws2, bs2, out0, out2, E);
    triplet_kernel<<<2048, 256, 0, stream>>>(C, Dm, pos, tidx, bc1, Wc2, bc2, out1, T);
}